// Round 12
// baseline (148.079 us; speedup 1.0000x reference)
//
#include <hip/hip_runtime.h>
#include <hip/hip_bf16.h>
#include <cstdint>

#define T_TOK 4096
#define D_DIM 1024
#define E_EXP 8
#define CAP   640          // int(1.25 * 4096 / 8)
#define MAXDROP 3456
#define MT    10           // 64-row m-tiles per expert (CAP/64)
#define GBLK  1024         // gating blocks (4 tokens each)
#define NSUB  32           // K subtiles of 32 (D_DIM/32)

typedef __attribute__((ext_vector_type(8))) short short8;
typedef __attribute__((ext_vector_type(4))) float f32x4;

// round-to-nearest-even float -> bf16 bits
__device__ inline unsigned short f2bf(float f) {
    uint32_t u = __float_as_uint(f);
    u += 0x7fffu + ((u >> 16) & 1u);
    return (unsigned short)(u >> 16);
}

// async global->LDS DMA: per-lane global address (g is this lane's 16-B slice),
// wave-uniform LDS base; HW writes lane's data at ldsbase + lane*16.
__device__ inline void dma16(const void* g, void* l) {
    __builtin_amdgcn_global_load_lds(
        (const __attribute__((address_space(1))) unsigned int*)g,
        (__attribute__((address_space(3))) unsigned int*)l, 16, 0, 0);
}

// tile base in tiled bf16 image: planes g=0..7, each [64 rows][8 shorts] = 1 KB
#define WB_TILE(e, nt, kt) ((((size_t)(e) * 16 + (nt)) * 16 + (kt)) * 4096)
#define XG_TILE(e, mt, kt) ((((size_t)(e) * MT + (mt)) * 16 + (kt)) * 4096)

// ---------------- prep (R7 version, measured ~12 us: near roofline) ----------------
__global__ __launch_bounds__(256) void prep_kernel(
    const float* __restrict__ x, const float* __restrict__ Wg,
    const float* __restrict__ bg, const float* __restrict__ W,
    unsigned short* __restrict__ Wb,
    int* __restrict__ top_idx, float* __restrict__ top_prob,
    float* __restrict__ blkpart)
{
    int bid = blockIdx.x;
    int tid = threadIdx.x;

    if (bid >= GBLK) {
        // ---- W transpose-convert, register-gather version ----
        int bid2 = (bid - GBLK) * 2;     // first tile; pair shares e,kt (nt = even,odd)
        int e   = bid2 >> 8;
        int kt  = (bid2 >> 4) & 15;
        int ntA = bid2 & 15;
        int k0  = kt * 64;
        const float* Wsrc = W + (size_t)e * D_DIM * D_DIM + (size_t)k0 * D_DIM;

        int c0 = tid, c1 = tid + 256;
        int g0 = c0 >> 6, n0c = c0 & 63;
        int g1 = c1 >> 6, n1c = c1 & 63;

        #pragma unroll
        for (int half = 0; half < 2; half++) {
            int n0 = (ntA + half) * 64;
            unsigned short* dst = Wb + WB_TILE(e, ntA + half, kt);
            const float* s0 = Wsrc + (size_t)(g0 * 8) * D_DIM + n0 + n0c;
            const float* s1 = Wsrc + (size_t)(g1 * 8) * D_DIM + n0 + n1c;
            float v[8], u[8];
            #pragma unroll
            for (int z = 0; z < 8; z++) v[z] = s0[(size_t)z * D_DIM];
            #pragma unroll
            for (int z = 0; z < 8; z++) u[z] = s1[(size_t)z * D_DIM];
            short8 a, b2;
            #pragma unroll
            for (int z = 0; z < 8; z++) { a[z] = (short)f2bf(v[z]); b2[z] = (short)f2bf(u[z]); }
            *(short8*)&dst[(size_t)c0 * 8] = a;
            *(short8*)&dst[(size_t)c1 * 8] = b2;
        }
    } else {
        // ---- gating ----
        __shared__ float probs_sm[4][8];
        int wid  = tid >> 6;
        int lane = tid & 63;
        int t = bid * 4 + wid;

        const float* xr = x + (size_t)t * D_DIM;

        float acc[8];
        #pragma unroll
        for (int e = 0; e < 8; e++) acc[e] = 0.f;

        #pragma unroll
        for (int ii = 0; ii < 16; ii++) {
            int d = lane + 64 * ii;
            float xv = xr[d];
            const float4* wr = (const float4*)(Wg + (size_t)d * 8);
            float4 a = wr[0], bq = wr[1];
            acc[0] += xv * a.x;  acc[1] += xv * a.y;
            acc[2] += xv * a.z;  acc[3] += xv * a.w;
            acc[4] += xv * bq.x; acc[5] += xv * bq.y;
            acc[6] += xv * bq.z; acc[7] += xv * bq.w;
        }
        #pragma unroll
        for (int off = 32; off > 0; off >>= 1) {
            #pragma unroll
            for (int e = 0; e < 8; e++) acc[e] += __shfl_xor(acc[e], off, 64);
        }
        if (lane == 0) {
            float lg[8];
            #pragma unroll
            for (int e = 0; e < 8; e++) lg[e] = acc[e] + bg[e];
            float m = lg[0]; int am = 0;
            #pragma unroll
            for (int e = 1; e < 8; e++) { if (lg[e] > m) { m = lg[e]; am = e; } }
            float ex[8], s = 0.f;
            #pragma unroll
            for (int e = 0; e < 8; e++) { ex[e] = __expf(lg[e] - m); s += ex[e]; }
            float inv = 1.f / s;
            top_idx[t]  = am;
            top_prob[t] = ex[am] * inv;
            #pragma unroll
            for (int e = 0; e < 8; e++) probs_sm[wid][e] = ex[e] * inv;
        }
        __syncthreads();
        if (tid < 8) {
            float s = probs_sm[0][tid] + probs_sm[1][tid]
                    + probs_sm[2][tid] + probs_sm[3][tid];
            blkpart[(size_t)bid * 8 + tid] = s;
        }
    }
}

// ---------------- gather + fused dispatch scan ----------------
// bid < 1280     : (e,mt,kt) stage x rows -> xg. Wave 0 recomputes this expert's
//                  dispatch positions from top_idx (64 ballot iters, ~0.5 us,
//                  hidden under block-level TLP); kt==0 writes the tok_list slice.
// bid 1280..1287 : per-expert dropped-row zeroing (usually none).
// bid 1288       : aux loss + cnt[] (counts + blkpart reduction).
// Replaces the serialized 1-block scan_kernel + one launch boundary.
__global__ __launch_bounds__(256) void gather_kernel(
    const float* __restrict__ x, const int* __restrict__ top_idx,
    const float* __restrict__ blkpart,
    int* __restrict__ tok_list, int* __restrict__ cnt,
    unsigned short* __restrict__ xg,
    float* __restrict__ out, float* __restrict__ out_aux)
{
    int bid  = blockIdx.x;
    int tid  = threadIdx.x;
    int lane = tid & 63, wv = tid >> 6;
    unsigned long long ltmask = (lane == 0) ? 0ull : ((~0ull) >> (64 - lane));

    if (bid < E_EXP * MT * 16) {
        __shared__ int tok_sm[64];
        __shared__ int count_sm;
        int e   = bid / (MT * 16);
        int rem = bid % (MT * 16);
        int mt  = rem >> 4, kt = rem & 15;
        int m0  = mt * 64;

        if (wv == 0) {
            int run = 0;
            #pragma unroll 1
            for (int c = 0; c < 64; c++) {
                int idxv = top_idx[c * 64 + lane];
                unsigned long long mk = __ballot(idxv == e);
                if (idxv == e) {
                    int pos = run + __popcll(mk & ltmask);
                    if (pos >= m0 && pos < m0 + 64) tok_sm[pos - m0] = c * 64 + lane;
                }
                run += __popcll(mk);
            }
            if (lane == 0) count_sm = run < CAP ? run : CAP;
        }
        __syncthreads();
        int count = count_sm;
        if (m0 >= count) return;

        // pad partial tile rows with the last valid token (old tl[count-1] semantics)
        if (wv == 0 && count < m0 + 64) {
            int last = count - 1 - m0;          // >= 0 since m0 < count
            if (lane > last) tok_sm[lane] = tok_sm[last];
        }
        __syncthreads();

        if (kt == 0 && tid < 64 && m0 + tid < count)
            tok_list[e * CAP + m0 + tid] = tok_sm[tid];

        unsigned short* dst = xg + XG_TILE(e, mt, kt);
        #pragma unroll
        for (int p = 0; p < 2; p++) {
            int c = tid + 256 * p;     // chunk = g*64 + row
            int g = c >> 6, row = c & 63;
            int tok = tok_sm[row];
            const float* src = x + (size_t)tok * D_DIM + kt * 64 + g * 8;
            float4 v0 = *(const float4*)(src);
            float4 v1 = *(const float4*)(src + 4);
            short8 v;
            v[0] = f2bf(v0.x); v[1] = f2bf(v0.y); v[2] = f2bf(v0.z); v[3] = f2bf(v0.w);
            v[4] = f2bf(v1.x); v[5] = f2bf(v1.y); v[6] = f2bf(v1.z); v[7] = f2bf(v1.w);
            *(short8*)&dst[(size_t)c * 8] = v;   // coalesced
        }
    } else if (bid < E_EXP * MT * 16 + E_EXP) {
        // ---- dropped-row zeroing for expert e ----
        __shared__ int droplist[MAXDROP];
        __shared__ int ndrop;
        int e = bid - E_EXP * MT * 16;
        if (tid == 0) ndrop = 0;
        __syncthreads();
        if (wv == 0) {
            int run = 0;
            #pragma unroll 1
            for (int c = 0; c < 64; c++) {
                int idxv = top_idx[c * 64 + lane];
                unsigned long long mk = __ballot(idxv == e);
                if (idxv == e) {
                    int pos = run + __popcll(mk & ltmask);
                    if (pos >= CAP) {
                        int di = atomicAdd(&ndrop, 1);
                        droplist[di] = c * 64 + lane;
                    }
                }
                run += __popcll(mk);
            }
        }
        __syncthreads();
        int nd = ndrop;
        float4 z = {0.f, 0.f, 0.f, 0.f};
        for (int d = 0; d < nd; d++) {
            int row = droplist[d];
            *(float4*)&out[(size_t)row * D_DIM + tid * 4] = z;
        }
    } else {
        // ---- aux loss + cnt[] ----
        __shared__ float wpartP[4][8];
        __shared__ int   wpartC[4][8];
        __shared__ float prod[8];

        float p[8]; int c8[8];
        #pragma unroll
        for (int e = 0; e < 8; e++) { p[e] = 0.f; c8[e] = 0; }

        #pragma unroll
        for (int r = 0; r < 4; r++) {
            const float* bp = blkpart + (size_t)(tid * 4 + r) * 8;
            #pragma unroll
            for (int e = 0; e < 8; e++) p[e] += bp[e];
        }
        #pragma unroll
        for (int r = 0; r < 16; r++) {
            int idxv = top_idx[tid * 16 + r];
            #pragma unroll
            for (int e = 0; e < 8; e++) c8[e] += (idxv == e);
        }
        #pragma unroll
        for (int off = 32; off > 0; off >>= 1) {
            #pragma unroll
            for (int e = 0; e < 8; e++) {
                p[e]  += __shfl_xor(p[e], off, 64);
                c8[e] += __shfl_xor(c8[e], off, 64);
            }
        }
        if (lane == 0) {
            #pragma unroll
            for (int e = 0; e < 8; e++) { wpartP[wv][e] = p[e]; wpartC[wv][e] = c8[e]; }
        }
        __syncthreads();
        if (tid < 8) {
            int tot  = wpartC[0][tid] + wpartC[1][tid] + wpartC[2][tid] + wpartC[3][tid];
            float Pe = wpartP[0][tid] + wpartP[1][tid] + wpartP[2][tid] + wpartP[3][tid];
            cnt[tid] = tot < CAP ? tot : CAP;
            prod[tid] = ((float)tot / (float)T_TOK) * (Pe / (float)T_TOK);
        }
        __syncthreads();
        if (tid == 0) {
            float s = 0.f;
            #pragma unroll
            for (int e = 0; e < 8; e++) s += prod[e];
            out_aux[0] = (float)E_EXP * s;
        }
    }
}

// ---------------- expert GEMM: 128x128 tile, 8 waves, BK=32, 3-buf counted vmcnt ----------------
// R11 version (measured win): wave w owns a 64x32 quadrant; per subtile
// vmcnt(2)+s_barrier keeps next subtile's DMAs in flight across the barrier.
__global__ __launch_bounds__(512) void expert_gemm(
    const unsigned short* __restrict__ xg, const unsigned short* __restrict__ Wb,
    const float* __restrict__ bias,
    const int* __restrict__ tok_list, const int* __restrict__ cnt,
    const float* __restrict__ top_prob, float* __restrict__ out)
{
    int bid = blockIdx.x;              // 8 e * 5 mtb * 8 ntb = 320
    int e   = bid / 40;
    int rem = bid % 40;
    int mtb = rem >> 3, ntb = rem & 7;
    int count = cnt[e];
    int m0 = mtb * 128;
    if (m0 >= count) return;
    int n0 = ntb * 128;

    // [buf][half][g(0..3)][row 0..63][8 bf16] : 8 KB per buf per operand
    __shared__ unsigned short Ab[3][2][4][64][8];   // 24 KB
    __shared__ unsigned short Bb[3][2][4][64][8];   // 24 KB

    int tid  = threadIdx.x;
    int lane = tid & 63, w = tid >> 6;          // 8 waves
    int quad = lane >> 4, l16 = lane & 15;
    int wr = w >> 2, wc = w & 3;                // wave quadrant: rows wr*64, cols wc*32

    const int* tl = tok_list + e * CAP;

    // staging role: waves 0-3 -> A, 4-7 -> B; each wave stages planes (wa&1)*2+{0,1}
    // of half wa>>1 per subtile.
    int  wa    = w & 3;
    int  shalf = wa >> 1;
    int  sg0   = (wa & 1) * 2;
    const unsigned short* sbase =
        (w < 4) ? (xg + XG_TILE(e, 2 * mtb + shalf, 0) + (size_t)lane * 8)
                : (Wb + WB_TILE(e, 2 * ntb + shalf, 0) + (size_t)lane * 8);

    #define STAGE(s, buf) do {                                                  \
        size_t off_ = (size_t)((s) >> 1) * 4096 + (size_t)((s) & 1) * 2048;     \
        if (w < 4) {                                                            \
            dma16(sbase + off_ + (size_t)sg0 * 512,       &Ab[buf][shalf][sg0][0][0]);     \
            dma16(sbase + off_ + (size_t)(sg0 + 1) * 512, &Ab[buf][shalf][sg0 + 1][0][0]); \
        } else {                                                                \
            dma16(sbase + off_ + (size_t)sg0 * 512,       &Bb[buf][shalf][sg0][0][0]);     \
            dma16(sbase + off_ + (size_t)(sg0 + 1) * 512, &Bb[buf][shalf][sg0 + 1][0][0]); \
        }                                                                       \
    } while (0)

    f32x4 acc[4][2];
    #pragma unroll
    for (int i = 0; i < 4; i++)
        #pragma unroll
        for (int j = 0; j < 2; j++)
            acc[i][j] = (f32x4){0.f, 0.f, 0.f, 0.f};

    // prologue: subtiles 0 and 1 in flight (4 DMAs/wave)
    STAGE(0, 0);
    STAGE(1, 1);

    #pragma unroll 1
    for (int s = 0; s < NSUB; s++) {
        // wait for subtile s (my oldest 2 DMAs); s+1's 2 stay in flight
        if (s + 1 < NSUB) { asm volatile("s_waitcnt vmcnt(2)" ::: "memory"); }
        else              { asm volatile("s_waitcnt vmcnt(0)" ::: "memory"); }
        __builtin_amdgcn_s_barrier();
        __builtin_amdgcn_sched_barrier(0);

        int cur = s % 3;
        if (s + 2 < NSUB)
            STAGE(s + 2, (s + 2) % 3);   // buf held subtile s-1: consumed pre-barrier

        short8 af[4], bf[2];
        #pragma unroll
        for (int i = 0; i < 4; i++)
            af[i] = *(const short8*)&Ab[cur][wr][quad][16 * i + l16][0];
        #pragma unroll
        for (int j = 0; j < 2; j++) {
            int cb = wc * 32 + 16 * j;           // 0..112, compile-time per (wc,j)
            bf[j] = *(const short8*)&Bb[cur][cb >> 6][quad][(cb & 63) + l16][0];
        }
        #pragma unroll
        for (int i = 0; i < 4; i++)
            #pragma unroll
            for (int j = 0; j < 2; j++)
                acc[i][j] = __builtin_amdgcn_mfma_f32_16x16x32_bf16(
                    af[i], bf[j], acc[i][j], 0, 0, 0);
    }
    #undef STAGE

    float bv[2];
    #pragma unroll
    for (int j = 0; j < 2; j++)
        bv[j] = bias[e * D_DIM + n0 + wc * 32 + 16 * j + l16];

    #pragma unroll
    for (int i = 0; i < 4; i++) {
        int rb = m0 + wr * 64 + 16 * i + quad * 4;
        #pragma unroll
        for (int r = 0; r < 4; r++) {
            int gm = rb + r;
            if (gm >= count) continue;
            int tok = tl[gm];
            float p = top_prob[tok];
            float* orow = out + (size_t)tok * D_DIM + n0 + wc * 32 + l16;
            #pragma unroll
            for (int j = 0; j < 2; j++)
                orow[16 * j] = (acc[i][j][r] + bv[j]) * p;
        }
    }
}

extern "C" void kernel_launch(void* const* d_in, const int* in_sizes, int n_in,
                              void* d_out, int out_size, void* d_ws, size_t ws_size,
                              hipStream_t stream) {
    const float* x  = (const float*)d_in[0];   // [4096,1024]
    const float* Wg = (const float*)d_in[1];   // [1024,8]
    const float* bg = (const float*)d_in[2];   // [8]
    const float* W  = (const float*)d_in[3];   // [8,1024,1024]
    const float* b  = (const float*)d_in[4];   // [8,1024]
    float* out = (float*)d_out;                // [4096*1024 + 1]

    char* ws = (char*)d_ws;                    // ~27.3 MiB used
    unsigned short* Wb = (unsigned short*)(ws + 0);          // 16,777,216 B (tiled)
    unsigned short* xg = (unsigned short*)(ws + 16777216);   // 10,485,760 B (tiled)
    int*   top_idx  = (int*)(ws + 27262976);   // 16384 B
    float* top_prob = (float*)(ws + 27279360); // 16384 B
    int*   tok_list = (int*)(ws + 27295744);   // 20480 B
    int*   cnt      = (int*)(ws + 27316224);   // 32 B
    float* blkpart  = (float*)(ws + 27316256); // 32768 B

    hipLaunchKernelGGL(prep_kernel, dim3(GBLK + 1024), dim3(256), 0, stream,
                       x, Wg, bg, W, Wb, top_idx, top_prob, blkpart);
    hipLaunchKernelGGL(gather_kernel, dim3(E_EXP * MT * 16 + E_EXP + 1), dim3(256), 0, stream,
                       x, top_idx, blkpart, tok_list, cnt, xg,
                       out, out + (size_t)T_TOK * D_DIM);
    hipLaunchKernelGGL(expert_gemm, dim3(E_EXP * 5 * 8), dim3(512), 0, stream,
                       xg, Wb, b, tok_list, cnt, top_prob, out);
}

// Round 13
// 138.473 us; speedup vs baseline: 1.0694x; 1.0694x over previous
//
#include <hip/hip_runtime.h>
#include <hip/hip_bf16.h>
#include <cstdint>

#define T_TOK 4096
#define D_DIM 1024
#define E_EXP 8
#define CAP   640          // int(1.25 * 4096 / 8)
#define MAXDROP 3456
#define MT    10           // 64-row m-tiles per expert (CAP/64)
#define GBLK  1024         // gating blocks (4 tokens each)
#define NSUB  32           // K subtiles of 32 (D_DIM/32)

typedef __attribute__((ext_vector_type(8))) short short8;
typedef __attribute__((ext_vector_type(4))) float f32x4;

// round-to-nearest-even float -> bf16 bits
__device__ inline unsigned short f2bf(float f) {
    uint32_t u = __float_as_uint(f);
    u += 0x7fffu + ((u >> 16) & 1u);
    return (unsigned short)(u >> 16);
}

// async global->LDS DMA: per-lane global address (g is this lane's 16-B slice),
// wave-uniform LDS base; HW writes lane's data at ldsbase + lane*16.
__device__ inline void dma16(const void* g, void* l) {
    __builtin_amdgcn_global_load_lds(
        (const __attribute__((address_space(1))) unsigned int*)g,
        (__attribute__((address_space(3))) unsigned int*)l, 16, 0, 0);
}

// tile base in tiled bf16 image: planes g=0..7, each [64 rows][8 shorts] = 1 KB
#define WB_TILE(e, nt, kt) ((((size_t)(e) * 16 + (nt)) * 16 + (kt)) * 4096)
#define XG_TILE(e, mt, kt) ((((size_t)(e) * MT + (mt)) * 16 + (kt)) * 4096)

// ---------------- prep (R7 version, measured ~12 us: near roofline) ----------------
__global__ __launch_bounds__(256) void prep_kernel(
    const float* __restrict__ x, const float* __restrict__ Wg,
    const float* __restrict__ bg, const float* __restrict__ W,
    unsigned short* __restrict__ Wb,
    int* __restrict__ top_idx, float* __restrict__ top_prob,
    float* __restrict__ blkpart)
{
    int bid = blockIdx.x;
    int tid = threadIdx.x;

    if (bid >= GBLK) {
        // ---- W transpose-convert, register-gather version ----
        int bid2 = (bid - GBLK) * 2;     // first tile; pair shares e,kt (nt = even,odd)
        int e   = bid2 >> 8;
        int kt  = (bid2 >> 4) & 15;
        int ntA = bid2 & 15;
        int k0  = kt * 64;
        const float* Wsrc = W + (size_t)e * D_DIM * D_DIM + (size_t)k0 * D_DIM;

        int c0 = tid, c1 = tid + 256;
        int g0 = c0 >> 6, n0c = c0 & 63;
        int g1 = c1 >> 6, n1c = c1 & 63;

        #pragma unroll
        for (int half = 0; half < 2; half++) {
            int n0 = (ntA + half) * 64;
            unsigned short* dst = Wb + WB_TILE(e, ntA + half, kt);
            const float* s0 = Wsrc + (size_t)(g0 * 8) * D_DIM + n0 + n0c;
            const float* s1 = Wsrc + (size_t)(g1 * 8) * D_DIM + n0 + n1c;
            float v[8], u[8];
            #pragma unroll
            for (int z = 0; z < 8; z++) v[z] = s0[(size_t)z * D_DIM];
            #pragma unroll
            for (int z = 0; z < 8; z++) u[z] = s1[(size_t)z * D_DIM];
            short8 a, b2;
            #pragma unroll
            for (int z = 0; z < 8; z++) { a[z] = (short)f2bf(v[z]); b2[z] = (short)f2bf(u[z]); }
            *(short8*)&dst[(size_t)c0 * 8] = a;
            *(short8*)&dst[(size_t)c1 * 8] = b2;
        }
    } else {
        // ---- gating ----
        __shared__ float probs_sm[4][8];
        int wid  = tid >> 6;
        int lane = tid & 63;
        int t = bid * 4 + wid;

        const float* xr = x + (size_t)t * D_DIM;

        float acc[8];
        #pragma unroll
        for (int e = 0; e < 8; e++) acc[e] = 0.f;

        #pragma unroll
        for (int ii = 0; ii < 16; ii++) {
            int d = lane + 64 * ii;
            float xv = xr[d];
            const float4* wr = (const float4*)(Wg + (size_t)d * 8);
            float4 a = wr[0], bq = wr[1];
            acc[0] += xv * a.x;  acc[1] += xv * a.y;
            acc[2] += xv * a.z;  acc[3] += xv * a.w;
            acc[4] += xv * bq.x; acc[5] += xv * bq.y;
            acc[6] += xv * bq.z; acc[7] += xv * bq.w;
        }
        #pragma unroll
        for (int off = 32; off > 0; off >>= 1) {
            #pragma unroll
            for (int e = 0; e < 8; e++) acc[e] += __shfl_xor(acc[e], off, 64);
        }
        if (lane == 0) {
            float lg[8];
            #pragma unroll
            for (int e = 0; e < 8; e++) lg[e] = acc[e] + bg[e];
            float m = lg[0]; int am = 0;
            #pragma unroll
            for (int e = 1; e < 8; e++) { if (lg[e] > m) { m = lg[e]; am = e; } }
            float ex[8], s = 0.f;
            #pragma unroll
            for (int e = 0; e < 8; e++) { ex[e] = __expf(lg[e] - m); s += ex[e]; }
            float inv = 1.f / s;
            top_idx[t]  = am;
            top_prob[t] = ex[am] * inv;
            #pragma unroll
            for (int e = 0; e < 8; e++) probs_sm[wid][e] = ex[e] * inv;
        }
        __syncthreads();
        if (tid < 8) {
            float s = probs_sm[0][tid] + probs_sm[1][tid]
                    + probs_sm[2][tid] + probs_sm[3][tid];
            blkpart[(size_t)bid * 8 + tid] = s;
        }
    }
}

// ---------------- scan: capacity dispatch + aux loss, 1 block x 1024 thr ----------------
__global__ __launch_bounds__(1024) void scan_kernel(
    const int* __restrict__ top_idx,
    int* __restrict__ tok_list, int* __restrict__ cnt,
    const float* __restrict__ blkpart,
    float* __restrict__ out, float* __restrict__ out_aux)
{
    __shared__ int counts[64][8];
    __shared__ int excl[64][8];
    __shared__ int fulltot[8];
    __shared__ int droplist[MAXDROP];
    __shared__ int ndrop;
    __shared__ float wpart[16][8];

    int tid  = threadIdx.x;
    int wv   = tid >> 6;
    int lane = tid & 63;
    unsigned long long ltmask = (lane == 0) ? 0ull : ((~0ull) >> (64 - lane));

    if (tid == 0) ndrop = 0;

    // prefetch this thread's slice of the prob partials (32 KB total, L2-hit)
    float p[8];
    {
        const float4* bp = (const float4*)(blkpart + (size_t)tid * 8);
        float4 p0 = bp[0], p1 = bp[1];
        p[0] = p0.x; p[1] = p0.y; p[2] = p0.z; p[3] = p0.w;
        p[4] = p1.x; p[5] = p1.y; p[6] = p1.z; p[7] = p1.w;
    }

    int ecache[4];
    #pragma unroll
    for (int c = 0; c < 4; c++)
        ecache[c] = top_idx[(4 * wv + c) * 64 + lane];

    #pragma unroll
    for (int c = 0; c < 4; c++) {
        int chunk = 4 * wv + c;
        int e = ecache[c];
        #pragma unroll
        for (int q = 0; q < 8; q++) {
            unsigned long long mk = __ballot(e == q);
            int tot = __popcll(mk);
            if (lane == q) counts[chunk][q] = tot;
        }
    }
    __syncthreads();

    if (wv == 0) {
        #pragma unroll
        for (int q = 0; q < 8; q++) {
            int v = counts[lane][q];
            int orig = v;
            #pragma unroll
            for (int off = 1; off < 64; off <<= 1) {
                int n = __shfl_up(v, off, 64);
                if (lane >= off) v += n;
            }
            excl[lane][q] = v - orig;
            int total = __shfl(v, 63, 64);
            if (lane == 0) {
                fulltot[q] = total;
                cnt[q] = total < CAP ? total : CAP;
            }
        }
    }
    __syncthreads();

    #pragma unroll
    for (int c = 0; c < 4; c++) {
        int chunk = 4 * wv + c;
        int t = chunk * 64 + lane;
        int e = ecache[c];
        int pos = 0;
        #pragma unroll
        for (int q = 0; q < 8; q++) {
            unsigned long long mk = __ballot(e == q);
            if (e == q) pos = excl[chunk][q] + __popcll(mk & ltmask);
        }
        if (pos < CAP) {
            tok_list[e * CAP + pos] = t;
        } else {
            int di = atomicAdd(&ndrop, 1);
            droplist[di] = t;
        }
    }

    // reduce prob partials: per-wave shuffle, then one lane per wave to LDS
    #pragma unroll
    for (int off = 32; off > 0; off >>= 1) {
        #pragma unroll
        for (int e = 0; e < 8; e++) p[e] += __shfl_xor(p[e], off, 64);
    }
    if (lane == 0) {
        #pragma unroll
        for (int e = 0; e < 8; e++) wpart[wv][e] = p[e];
    }
    __syncthreads();

    // zero dropped rows (usually none)
    int nd = ndrop;
    int grp = tid >> 8;
    int col = (tid & 255) * 4;
    float4 z = {0.f, 0.f, 0.f, 0.f};
    for (int d = grp; d < nd; d += 4) {
        int row = droplist[d];
        *(float4*)&out[(size_t)row * D_DIM + col] = z;
    }

    // aux loss: E * sum_e (fullcnt_e/T) * (mean_t probs_te)
    if (tid == 0) {
        float s = 0.f;
        #pragma unroll
        for (int e = 0; e < 8; e++) {
            float Pe = 0.f;
            #pragma unroll
            for (int w = 0; w < 16; w++) Pe += wpart[w][e];
            s += ((float)fulltot[e] / (float)T_TOK) * (Pe / (float)T_TOK);
        }
        out_aux[0] = (float)E_EXP * s;
    }
}

// ---------------- gather: x fp32 rows -> xg tiled bf16 [e][mt][kt][g][row][8] ----------------
__global__ __launch_bounds__(256) void gather_kernel(
    const float* __restrict__ x, const int* __restrict__ tok_list,
    const int* __restrict__ cnt, unsigned short* __restrict__ xg)
{
    int bid = blockIdx.x;              // 8 e * 10 mt * 16 kt = 1280
    int e   = bid / (MT * 16);
    int rem = bid % (MT * 16);
    int mt  = rem >> 4, kt = rem & 15;
    int count = cnt[e];
    int m0 = mt * 64;
    if (m0 >= count) return;

    int tid = threadIdx.x;
    const int* tl = tok_list + e * CAP;
    unsigned short* dst = xg + XG_TILE(e, mt, kt);

    #pragma unroll
    for (int p = 0; p < 2; p++) {
        int c = tid + 256 * p;     // chunk = g*64 + row
        int g = c >> 6, row = c & 63;
        int gm = m0 + row;
        int tok = tl[gm < count ? gm : count - 1];
        const float* src = x + (size_t)tok * D_DIM + kt * 64 + g * 8;
        float4 v0 = *(const float4*)(src);
        float4 v1 = *(const float4*)(src + 4);
        short8 v;
        v[0] = f2bf(v0.x); v[1] = f2bf(v0.y); v[2] = f2bf(v0.z); v[3] = f2bf(v0.w);
        v[4] = f2bf(v1.x); v[5] = f2bf(v1.y); v[6] = f2bf(v1.z); v[7] = f2bf(v1.w);
        *(short8*)&dst[(size_t)c * 8] = v;   // coalesced
    }
}

// ---------------- expert GEMM: 128x128 tile, 8 waves, BK=32, 3-buf counted vmcnt ----------------
// R11 structure (measured win) + XCD-chunked swizzle: bid = (orig&7)*40 + orig>>3
// (bijective, 320 = 8x40). Dispatch round-robins orig across XCDs, so each XCD
// gets one whole expert: its Wb slice (2 MB) + xg slice (1.25 MB) fit in the 4 MB
// per-XCD L2, making all A/B panel re-reads (8 ntb x 5 mtb sharing) local L2 hits
// instead of scattering each panel into up to 8 different L2s.
__global__ __launch_bounds__(512) void expert_gemm(
    const unsigned short* __restrict__ xg, const unsigned short* __restrict__ Wb,
    const float* __restrict__ bias,
    const int* __restrict__ tok_list, const int* __restrict__ cnt,
    const float* __restrict__ top_prob, float* __restrict__ out)
{
    int orig = blockIdx.x;             // 8 e * 5 mtb * 8 ntb = 320
    int bid  = (orig & 7) * 40 + (orig >> 3);   // XCD-chunked: one expert per XCD
    int e   = bid / 40;
    int rem = bid % 40;
    int mtb = rem >> 3, ntb = rem & 7;
    int count = cnt[e];
    int m0 = mtb * 128;
    if (m0 >= count) return;
    int n0 = ntb * 128;

    // [buf][half][g(0..3)][row 0..63][8 bf16] : 8 KB per buf per operand
    __shared__ unsigned short Ab[3][2][4][64][8];   // 24 KB
    __shared__ unsigned short Bb[3][2][4][64][8];   // 24 KB

    int tid  = threadIdx.x;
    int lane = tid & 63, w = tid >> 6;          // 8 waves
    int quad = lane >> 4, l16 = lane & 15;
    int wr = w >> 2, wc = w & 3;                // wave quadrant: rows wr*64, cols wc*32

    const int* tl = tok_list + e * CAP;

    // staging role: waves 0-3 -> A, 4-7 -> B; each wave stages planes (wa&1)*2+{0,1}
    // of half wa>>1 per subtile.
    int  wa    = w & 3;
    int  shalf = wa >> 1;
    int  sg0   = (wa & 1) * 2;
    const unsigned short* sbase =
        (w < 4) ? (xg + XG_TILE(e, 2 * mtb + shalf, 0) + (size_t)lane * 8)
                : (Wb + WB_TILE(e, 2 * ntb + shalf, 0) + (size_t)lane * 8);

    #define STAGE(s, buf) do {                                                  \
        size_t off_ = (size_t)((s) >> 1) * 4096 + (size_t)((s) & 1) * 2048;     \
        if (w < 4) {                                                            \
            dma16(sbase + off_ + (size_t)sg0 * 512,       &Ab[buf][shalf][sg0][0][0]);     \
            dma16(sbase + off_ + (size_t)(sg0 + 1) * 512, &Ab[buf][shalf][sg0 + 1][0][0]); \
        } else {                                                                \
            dma16(sbase + off_ + (size_t)sg0 * 512,       &Bb[buf][shalf][sg0][0][0]);     \
            dma16(sbase + off_ + (size_t)(sg0 + 1) * 512, &Bb[buf][shalf][sg0 + 1][0][0]); \
        }                                                                       \
    } while (0)

    f32x4 acc[4][2];
    #pragma unroll
    for (int i = 0; i < 4; i++)
        #pragma unroll
        for (int j = 0; j < 2; j++)
            acc[i][j] = (f32x4){0.f, 0.f, 0.f, 0.f};

    // prologue: subtiles 0 and 1 in flight (4 DMAs/wave)
    STAGE(0, 0);
    STAGE(1, 1);

    #pragma unroll 1
    for (int s = 0; s < NSUB; s++) {
        // wait for subtile s (my oldest 2 DMAs); s+1's 2 stay in flight
        if (s + 1 < NSUB) { asm volatile("s_waitcnt vmcnt(2)" ::: "memory"); }
        else              { asm volatile("s_waitcnt vmcnt(0)" ::: "memory"); }
        __builtin_amdgcn_s_barrier();
        __builtin_amdgcn_sched_barrier(0);

        int cur = s % 3;
        if (s + 2 < NSUB)
            STAGE(s + 2, (s + 2) % 3);   // buf held subtile s-1: consumed pre-barrier

        short8 af[4], bf[2];
        #pragma unroll
        for (int i = 0; i < 4; i++)
            af[i] = *(const short8*)&Ab[cur][wr][quad][16 * i + l16][0];
        #pragma unroll
        for (int j = 0; j < 2; j++) {
            int cb = wc * 32 + 16 * j;           // 0..112, compile-time per (wc,j)
            bf[j] = *(const short8*)&Bb[cur][cb >> 6][quad][(cb & 63) + l16][0];
        }
        #pragma unroll
        for (int i = 0; i < 4; i++)
            #pragma unroll
            for (int j = 0; j < 2; j++)
                acc[i][j] = __builtin_amdgcn_mfma_f32_16x16x32_bf16(
                    af[i], bf[j], acc[i][j], 0, 0, 0);
    }
    #undef STAGE

    float bv[2];
    #pragma unroll
    for (int j = 0; j < 2; j++)
        bv[j] = bias[e * D_DIM + n0 + wc * 32 + 16 * j + l16];

    #pragma unroll
    for (int i = 0; i < 4; i++) {
        int rb = m0 + wr * 64 + 16 * i + quad * 4;
        #pragma unroll
        for (int r = 0; r < 4; r++) {
            int gm = rb + r;
            if (gm >= count) continue;
            int tok = tl[gm];
            float p = top_prob[tok];
            float* orow = out + (size_t)tok * D_DIM + n0 + wc * 32 + l16;
            #pragma unroll
            for (int j = 0; j < 2; j++)
                orow[16 * j] = (acc[i][j][r] + bv[j]) * p;
        }
    }
}

extern "C" void kernel_launch(void* const* d_in, const int* in_sizes, int n_in,
                              void* d_out, int out_size, void* d_ws, size_t ws_size,
                              hipStream_t stream) {
    const float* x  = (const float*)d_in[0];   // [4096,1024]
    const float* Wg = (const float*)d_in[1];   // [1024,8]
    const float* bg = (const float*)d_in[2];   // [8]
    const float* W  = (const float*)d_in[3];   // [8,1024,1024]
    const float* b  = (const float*)d_in[4];   // [8,1024]
    float* out = (float*)d_out;                // [4096*1024 + 1]

    char* ws = (char*)d_ws;                    // ~27.3 MiB used
    unsigned short* Wb = (unsigned short*)(ws + 0);          // 16,777,216 B (tiled)
    unsigned short* xg = (unsigned short*)(ws + 16777216);   // 10,485,760 B (tiled)
    int*   top_idx  = (int*)(ws + 27262976);   // 16384 B
    float* top_prob = (float*)(ws + 27279360); // 16384 B
    int*   tok_list = (int*)(ws + 27295744);   // 20480 B
    int*   cnt      = (int*)(ws + 27316224);   // 32 B
    float* blkpart  = (float*)(ws + 27316256); // 32768 B

    hipLaunchKernelGGL(prep_kernel, dim3(GBLK + 1024), dim3(256), 0, stream,
                       x, Wg, bg, W, Wb, top_idx, top_prob, blkpart);
    hipLaunchKernelGGL(scan_kernel, dim3(1), dim3(1024), 0, stream,
                       top_idx, tok_list, cnt, blkpart, out, out + (size_t)T_TOK * D_DIM);
    hipLaunchKernelGGL(gather_kernel, dim3(E_EXP * MT * 16), dim3(256), 0, stream,
                       x, tok_list, cnt, xg);
    hipLaunchKernelGGL(expert_gemm, dim3(E_EXP * 5 * 8), dim3(512), 0, stream,
                       xg, Wb, b, tok_list, cnt, top_prob, out);
}